// Round 2
// baseline (312.030 us; speedup 1.0000x reference)
//
#include <hip/hip_runtime.h>
#include <hip/hip_cooperative_groups.h>

namespace cg = cooperative_groups;

typedef __bf16 bf16x8 __attribute__((ext_vector_type(8)));
typedef __bf16 bf16x4 __attribute__((ext_vector_type(4)));
typedef float f32x4 __attribute__((ext_vector_type(4)));

#define SLOTW 260  // per-row partial-slot stride floats (>= 4*NTv_max=256)

#define GLOAD_LDS16(g, l)                                                      \
  __builtin_amdgcn_global_load_lds(                                            \
      (const __attribute__((address_space(1))) void*)(g),                      \
      (__attribute__((address_space(3))) void*)(l), 16, 0, 0)

__device__ __forceinline__ void tri_decode(int blk, int NT, int& bi, int& bj) {
  int b = 0, rem = blk, span = NT;
  while (rem >= span) {
    rem -= span;
    b++;
    span--;
  }
  bi = b;
  bj = b + rem;
}

// bijective XCD swizzle over [0,n) (m204 formula)
__device__ __forceinline__ int xcd_swz(int w, int n) {
  const int q = n >> 3, r = n & 7, x = w & 7, o = w >> 3;
  return (x < r ? x * (q + 1) : r * (q + 1) + (x - r) * q) + o;
}

__device__ __forceinline__ bool tile_overlap(const unsigned char* gcode,
                                             size_t sA, int lastA,
                                             size_t rowB) {
  const int la0 = gcode[sA], la1 = gcode[sA + lastA];
  const int lb0 = gcode[rowB], lb1 = gcode[rowB + 127];
  const int hiA = la1 > 2 ? 2 : la1;
  const int hiB = lb1 > 2 ? 2 : lb1;
  const int lo = la0 > lb0 ? la0 : lb0;
  const int hi = hiA < hiB ? hiA : hiB;
  return (la0 <= 2) && (lb0 <= 2) && (lo <= hi);
}

// ======================= R11: single cooperative kernel =====================
// Phases separated by grid.sync() (device-scope fence, G16-safe):
//   A (block 0): label scan -> code/dst/hdr/gcode-pad, out[0]=0
//   B (all): normalize -> fng (bf16, gathered+sorted), fng pad zero
//   C (all): pass 1 GEMM tiles -> P expsum slots + Sc score cache
//   E (all): pass 2 from Sc -> P2 (1 slot per (row,tile): single writer);
//            E recomputed in-block from P (k_red kernel eliminated)
//   F (all): final reduce, one atomicAdd per block
// Grid = occupancy*256 (co-residency guaranteed); all phases grid-stride.
__global__ __launch_bounds__(512, 6) void k_fused(
    const float* __restrict__ X, const int* __restrict__ labels,
    const int* __restrict__ bad, unsigned char* __restrict__ code,
    int* __restrict__ dst, int* __restrict__ hdr, __bf16* __restrict__ fng,
    unsigned char* __restrict__ gcode, float* __restrict__ P,
    _Float16* __restrict__ Sc, float* __restrict__ P2,
    float* __restrict__ out, int Nv, int Dv) {
  const int t = threadIdx.x;
  const int G = gridDim.x;
  cg::grid_group grid = cg::this_grid();

  // 32KB As/Bs double-buffer (phase C); overlaid by colpart (phase E).
  // E_s tail is disjoint from colpart.
  __shared__ __align__(16) char smem[33792];
  auto As = (__bf16(*)[128 * 32])smem;              // [2][4096] = 16KB
  auto Bs = (__bf16(*)[128 * 32])(smem + 16384);    // [2][4096] = 16KB
  float* colpart = (float*)smem;                    // 32*132*4 = 16896B
  float* E_s = (float*)(smem + 32768);              // 256 floats
  __shared__ int wt[8][3], wo[9][3];
  __shared__ float sd[8];

  // ---------------- Phase A: scan (block 0 only) ----------------
  if (blockIdx.x == 0) {
    const int lane = t & 63, wv = t >> 6;
    const int per = Nv >> 9;  // rows/thread (16 at 8192)
    const int base = t * per;
    unsigned char lc[16];
    int cnt[3] = {0, 0, 0};
    for (int k = 0; k < per; ++k) {
      const int r = base + k;
      const unsigned char c =
          (bad[r] == 0) ? (unsigned char)labels[r] : (unsigned char)255;
      lc[k] = c;
      code[r] = c;
      if (c <= 2) cnt[c]++;
    }
    int inc0 = cnt[0], inc1 = cnt[1], inc2 = cnt[2];
#pragma unroll
    for (int off = 1; off < 64; off <<= 1) {
      const int a = __shfl_up(inc0, off);
      const int b = __shfl_up(inc1, off);
      const int c = __shfl_up(inc2, off);
      if (lane >= off) {
        inc0 += a;
        inc1 += b;
        inc2 += c;
      }
    }
    if (lane == 63) {
      wt[wv][0] = inc0;
      wt[wv][1] = inc1;
      wt[wv][2] = inc2;
    }
    __syncthreads();
    if (t == 0) {
      int s0 = 0, s1 = 0, s2 = 0;
      for (int w = 0; w < 8; ++w) {
        wo[w][0] = s0;
        wo[w][1] = s1;
        wo[w][2] = s2;
        s0 += wt[w][0];
        s1 += wt[w][1];
        s2 += wt[w][2];
      }
      wo[8][0] = s0;
      wo[8][1] = s1;
      wo[8][2] = s2;
    }
    __syncthreads();
    const int C0 = wo[8][0], C1 = wo[8][1], C2 = wo[8][2];
    int run[3];
    run[0] = wo[wv][0] + inc0 - cnt[0];
    run[1] = C0 + wo[wv][1] + inc1 - cnt[1];
    run[2] = C0 + C1 + wo[wv][2] + inc2 - cnt[2];
    for (int k = 0; k < per; ++k) {
      const int c = lc[k];
      dst[base + k] = (c <= 2) ? run[c]++ : -1;
    }
    const int Ml = C0 + C1 + C2;
    const int Mpadl = (Ml + 127) & ~127;
    if (t == 0) {
      const int NTl = Mpadl >> 7;
      hdr[0] = Ml;
      hdr[1] = Mpadl;
      hdr[2] = NTl;
      hdr[3] = NTl * (NTl + 1) / 2;
      hdr[4] = C0;
      hdr[5] = C1;
      hdr[6] = C2;
      int count = 1;
      if (C0 >= 2 && Ml > C0) count += C0;
      if (C1 >= 2 && Ml > C1) count += C1;
      if (C2 >= 2 && Ml > C2) count += C2;
      hdr[7] = count;
      out[0] = 0.f;  // phase F atomicAdds into this
    }
    for (int i = Ml + t; i < Mpadl; i += 512) gcode[i] = 255;
  }
  grid.sync();

  const int M = hdr[0], Mpad = hdr[1], NTv = hdr[2], ntri = hdr[3];

  // ---------------- Phase B: normalize (1 row per wave) ----------------
  {
    const int rsub = t >> 6, tl = t & 63;
    const int nw = Nv >> 3;  // 8 rows per block-iter
    if (Dv == 512) {
      for (int w = blockIdx.x; w < nw; w += G) {
        const int row = w * 8 + rsub;
        const unsigned char c = code[row];
        float4 v0 = {0.f, 0.f, 0.f, 0.f}, v1 = {0.f, 0.f, 0.f, 0.f};
        float ss = 0.f;
        if (c <= 2) {
          const float4* xr = (const float4*)(X + (size_t)row * Dv);
          v0 = xr[tl * 2];
          v1 = xr[tl * 2 + 1];
          ss = v0.x * v0.x + v0.y * v0.y + v0.z * v0.z + v0.w * v0.w +
               v1.x * v1.x + v1.y * v1.y + v1.z * v1.z + v1.w * v1.w;
        }
#pragma unroll
        for (int off = 32; off; off >>= 1) ss += __shfl_down(ss, off);
        ss = __shfl(ss, 0);
        if (c <= 2) {
          const float inv = 1.0f / sqrtf(ss);
          const int g = dst[row];
          bf16x8 o;
          o[0] = (__bf16)(v0.x * inv);
          o[1] = (__bf16)(v0.y * inv);
          o[2] = (__bf16)(v0.z * inv);
          o[3] = (__bf16)(v0.w * inv);
          o[4] = (__bf16)(v1.x * inv);
          o[5] = (__bf16)(v1.y * inv);
          o[6] = (__bf16)(v1.z * inv);
          o[7] = (__bf16)(v1.w * inv);
          *(bf16x8*)(fng + (size_t)g * Dv + tl * 8) = o;
          if (tl == 0) gcode[g] = c;
        }
      }
    } else {
      for (int w = blockIdx.x; w < nw; w += G) {
        const int row = w * 8 + rsub;
        const unsigned char c = code[row];
        if (c <= 2) {
          const float4* xr = (const float4*)(X + (size_t)row * Dv);
          float ss = 0.f;
          for (int idx = tl; idx < (Dv >> 2); idx += 64) {
            const float4 v = xr[idx];
            ss += v.x * v.x + v.y * v.y + v.z * v.z + v.w * v.w;
          }
#pragma unroll
          for (int off = 32; off; off >>= 1) ss += __shfl_down(ss, off);
          ss = __shfl(ss, 0);
          const float inv = 1.0f / sqrtf(ss);
          const int g = dst[row];
          for (int idx = tl; idx < (Dv >> 3); idx += 64) {
            const float4 u0 = xr[idx * 2];
            const float4 u1 = xr[idx * 2 + 1];
            bf16x8 o;
            o[0] = (__bf16)(u0.x * inv);
            o[1] = (__bf16)(u0.y * inv);
            o[2] = (__bf16)(u0.z * inv);
            o[3] = (__bf16)(u0.w * inv);
            o[4] = (__bf16)(u1.x * inv);
            o[5] = (__bf16)(u1.y * inv);
            o[6] = (__bf16)(u1.z * inv);
            o[7] = (__bf16)(u1.w * inv);
            *(bf16x8*)(fng + (size_t)g * Dv + idx * 8) = o;
          }
          if (tl == 0) gcode[g] = c;
        }
      }
    }
    // fng pad rows zero
    const int npad = (Mpad - M) * (Dv >> 3);
    float4* fp = (float4*)(fng + (size_t)M * Dv);
    const float4 z = {0.f, 0.f, 0.f, 0.f};
    for (int i = blockIdx.x * 512 + t; i < npad; i += G * 512) fp[i] = z;
  }
  grid.sync();

  // ---------------- Phase C: pass 1 GEMM (128x128 tiles) ----------------
  {
    const int lane = t & 63;
    const int wave = t >> 6;
    const int quad = lane >> 4;
    const int l16 = lane & 15;
    const int wr = (wave >> 1) * 32;
    const int wc = (wave & 1) * 64;
    const int r4 = t >> 2, q4 = t & 3;
    for (int w = blockIdx.x; w < ntri; w += G) {
      const int bid = xcd_swz(w, ntri);
      int bi, bj;
      tri_decode(bid, NTv, bi, bj);
      const size_t sA = (size_t)bi * 128;
      const size_t rowB = (size_t)bj * 128;
      f32x4 acc[2][4] = {};
      auto stage = [&](int k0, int b) {
        GLOAD_LDS16(fng + (sA + r4) * Dv + k0 + q4 * 8,
                    &As[b][(size_t)wave * 64 * 8]);
        GLOAD_LDS16(fng + (rowB + r4) * Dv + k0 + q4 * 8,
                    &Bs[b][(size_t)wave * 64 * 8]);
      };
      stage(0, 0);
      int buf = 0;
      for (int k0 = 0; k0 < Dv; k0 += 32) {
        __syncthreads();  // drains vmcnt: buf loads done; prev reads done
        if (k0 + 32 < Dv) stage(k0 + 32, buf ^ 1);
        bf16x8 af[2], bfv[4];
#pragma unroll
        for (int mi = 0; mi < 2; ++mi)
          af[mi] =
              *(const bf16x8*)&As[buf][(wr + mi * 16 + l16) * 32 + quad * 8];
#pragma unroll
        for (int ni = 0; ni < 4; ++ni)
          bfv[ni] =
              *(const bf16x8*)&Bs[buf][(wc + ni * 16 + l16) * 32 + quad * 8];
#pragma unroll
        for (int mi = 0; mi < 2; ++mi)
#pragma unroll
          for (int ni = 0; ni < 4; ++ni)
            acc[mi][ni] = __builtin_amdgcn_mfma_f32_16x16x32_bf16(
                af[mi], bfv[ni], acc[mi][ni], 0, 0, 0);
        buf ^= 1;
      }
      // C/D layout (verified m89/m91): col = lane&15, row = quad*4 + reg
      unsigned char ca[8], cb[4];
#pragma unroll
      for (int mi = 0; mi < 2; ++mi)
#pragma unroll
        for (int r = 0; r < 4; ++r)
          ca[mi * 4 + r] = gcode[sA + wr + mi * 16 + quad * 4 + r];
#pragma unroll
      for (int ni = 0; ni < 4; ++ni) cb[ni] = gcode[rowB + wc + ni * 16 + l16];
      const bool ov = tile_overlap(gcode, sA, 127, rowB);
      _Float16* St = Sc + (size_t)bid * 16384;

      float rowsum[8] = {};
      float colsum[4] = {};
#pragma unroll
      for (int mi = 0; mi < 2; ++mi)
#pragma unroll
        for (int ni = 0; ni < 4; ++ni)
#pragma unroll
          for (int r = 0; r < 4; ++r) {
            const float s = acc[mi][ni][r] * 10.0f;
            const float ex = __expf(s);
            const int a = ca[mi * 4 + r], b = cb[ni];
            const bool diff = a != b;
            rowsum[mi * 4 + r] += (b <= 2 && diff) ? ex : 0.f;
            colsum[ni] += (a <= 2 && diff) ? ex : 0.f;
            if (ov)
              St[(wr + mi * 16 + quad * 4 + r) * 128 + wc + ni * 16 + l16] =
                  (_Float16)s;
          }
#pragma unroll
      for (int off = 1; off < 16; off <<= 1)
#pragma unroll
        for (int k = 0; k < 8; ++k) rowsum[k] += __shfl_xor(rowsum[k], off);
      if (l16 == 0)
#pragma unroll
        for (int k = 0; k < 8; ++k) {
          const size_t base =
              (sA + wr + (k >> 2) * 16 + quad * 4 + (k & 3)) * SLOTW + bj * 4;
          P[base + (wave & 1)] = rowsum[k];
          P[base + 2 + (wave & 1)] = 0.f;
        }
      if (bi != bj) {
#pragma unroll
        for (int off = 16; off < 64; off <<= 1)
#pragma unroll
          for (int ni = 0; ni < 4; ++ni)
            colsum[ni] += __shfl_xor(colsum[ni], off);
        if (quad == 0)
#pragma unroll
          for (int ni = 0; ni < 4; ++ni)
            P[(rowB + wc + ni * 16 + l16) * SLOTW + bi * 4 + (wave >> 1)] =
                colsum[ni];
      }
    }
  }
  grid.sync();

  // ---------------- Phase E: pass 2 from Sc (full 128x128 tiles) ----------
  // P2 slot scheme: row g in row-tile tg gets NTv slots; slot k is written by
  // exactly one block: (tg,k) A-path for k>=tg, (k,tg) B-path for k<tg.
  {
    const int l8 = t & 15;
    const int rq = t >> 4;  // 0..31
    for (int w = blockIdx.x; w < ntri; w += G) {
      const int bid = xcd_swz(w, ntri);
      int bi, bj;
      tri_decode(bid, NTv, bi, bj);
      const size_t sA = (size_t)bi * 128;
      const size_t rowB = (size_t)bj * 128;
      const bool diag = (bi == bj);
      if (!tile_overlap(gcode, sA, 127, rowB)) {
        if (t < 128)
          P2[(sA + t) * SLOTW + bj] = 0.f;
        else if (t < 256 && !diag)
          P2[(rowB + t - 128) * SLOTW + bi] = 0.f;
        continue;
      }
      {  // E for this tile's 256 rows, from P (2 threads/row)
        const int rr = t >> 1, half = t & 1;
        const size_t g = (rr < 128) ? (sA + rr) : (rowB + (rr - 128));
        const float2* p = (const float2*)(P + g * SLOTW + half * 2 * NTv);
        float s = 0.f;
        for (int k = 0; k < NTv; ++k) s += p[k].x + p[k].y;
        s += __shfl_xor(s, 1);
        if (half == 0) E_s[rr] = s;
      }
      __syncthreads();
      const _Float16* St = Sc + (size_t)bid * 16384;
      unsigned char cbv[8];
      float eB[8];
      {
        const uint2 cv = *(const uint2*)(gcode + rowB + l8 * 8);
        const unsigned char* cp = (const unsigned char*)&cv;
#pragma unroll
        for (int e = 0; e < 8; ++e) cbv[e] = cp[e];
#pragma unroll
        for (int e = 0; e < 8; ++e) eB[e] = E_s[128 + l8 * 8 + e];
      }
      float colsum[8] = {};
#pragma unroll
      for (int k = 0; k < 4; ++k) {
        const int row = k * 32 + rq;
        const int a = gcode[sA + row];
        const float eA = E_s[row];
        const float4 sv = *(const float4*)(St + (size_t)row * 128 + l8 * 8);
        const _Float16* hp = (const _Float16*)&sv;
        float rsum = 0.f;
#pragma unroll
        for (int e = 0; e < 8; ++e) {
          const int col = l8 * 8 + e;
          const float em = __expf(-(float)hp[e]);
          const bool pos =
              (a == cbv[e]) && (cbv[e] <= 2) && !(diag && row == col);
          rsum += pos ? __logf(1.f + eA * em) : 0.f;
          colsum[e] += pos ? __logf(1.f + eB[e] * em) : 0.f;
        }
#pragma unroll
        for (int off = 1; off < 16; off <<= 1) rsum += __shfl_xor(rsum, off);
        if (l8 == 0) P2[(sA + row) * SLOTW + bj] = rsum;
      }
#pragma unroll
      for (int e = 0; e < 8; ++e) colpart[rq * 132 + l8 * 8 + e] = colsum[e];
      __syncthreads();
      if (t < 128 && !diag) {
        float cs = 0.f;
#pragma unroll
        for (int i = 0; i < 32; ++i) cs += colpart[i * 132 + t];
        P2[(rowB + t) * SLOTW + bi] = cs;
      }
      // next iteration's first __syncthreads (after E_s writes, which touch a
      // disjoint LDS region) protects colpart against overwrite-before-read
    }
  }
  grid.sync();

  // ---------------- Phase F: final reduce ----------------
  {
    const int c0 = hdr[4], c1 = hdr[5], c2 = hdr[6], cntv = hdr[7];
    const int vt = c0 + c1 + c2;
    float contrib = 0.f;
    for (int g = blockIdx.x * 512 + t; g < M; g += G * 512) {
      const int l = gcode[g];
      if (l <= 2) {
        const int cmy = (l == 0) ? c0 : ((l == 1) ? c1 : c2);
        if (vt - cmy > 0) {  // has negatives -> processed
          const int pos_cnt = cmy - 1;
          if (pos_cnt > 0) {
            float s = 0.f;
            const float* p = P2 + (size_t)g * SLOTW;
            for (int k = 0; k < NTv; ++k) s += p[k];
            contrib += s / (float)pos_cnt;
          } else {
            float e2 = 0.f;
            const float2* p = (const float2*)(P + (size_t)g * SLOTW);
            for (int k = 0; k < 2 * NTv; ++k) e2 += p[k].x + p[k].y;
            contrib += __logf(1.f + e2 * __expf(-10.0f));
          }
        }
      }
    }
#pragma unroll
    for (int off = 32; off; off >>= 1) contrib += __shfl_down(contrib, off);
    if ((t & 63) == 0) sd[t >> 6] = contrib;
    __syncthreads();
    if (t == 0) {
      float tot = 0.f;
#pragma unroll
      for (int i = 0; i < 8; ++i) tot += sd[i];
      if (tot != 0.f) atomicAdd(out, tot / (float)cntv);
    }
  }
}

// ===================== fallback: proven R1 six-kernel pipeline ==============
__global__ __launch_bounds__(1024) void k_scan(
    const int* __restrict__ labels, const int* __restrict__ bad,
    unsigned char* __restrict__ code, int* __restrict__ dst,
    int* __restrict__ hdr, __bf16* __restrict__ fng,
    unsigned char* __restrict__ gcode, float* __restrict__ out, int Nv,
    int Dv) {
  const int t = threadIdx.x;
  const int lane = t & 63, wv = t >> 6;
  const int per = Nv >> 10;
  const int base = t * per;
  unsigned char lc[8];
  int cnt[3] = {0, 0, 0};
  for (int k = 0; k < per; ++k) {
    const int r = base + k;
    const unsigned char c =
        (bad[r] == 0) ? (unsigned char)labels[r] : (unsigned char)255;
    lc[k] = c;
    code[r] = c;
    if (c <= 2) cnt[c]++;
  }
  int inc0 = cnt[0], inc1 = cnt[1], inc2 = cnt[2];
#pragma unroll
  for (int off = 1; off < 64; off <<= 1) {
    const int a = __shfl_up(inc0, off);
    const int b = __shfl_up(inc1, off);
    const int c = __shfl_up(inc2, off);
    if (lane >= off) {
      inc0 += a;
      inc1 += b;
      inc2 += c;
    }
  }
  __shared__ int wt[16][3], wo[17][3];
  if (lane == 63) {
    wt[wv][0] = inc0;
    wt[wv][1] = inc1;
    wt[wv][2] = inc2;
  }
  __syncthreads();
  if (t == 0) {
    int s0 = 0, s1 = 0, s2 = 0;
    for (int w = 0; w < 16; ++w) {
      wo[w][0] = s0;
      wo[w][1] = s1;
      wo[w][2] = s2;
      s0 += wt[w][0];
      s1 += wt[w][1];
      s2 += wt[w][2];
    }
    wo[16][0] = s0;
    wo[16][1] = s1;
    wo[16][2] = s2;
  }
  __syncthreads();
  const int C0 = wo[16][0], C1 = wo[16][1], C2 = wo[16][2];
  int run[3];
  run[0] = wo[wv][0] + inc0 - cnt[0];
  run[1] = C0 + wo[wv][1] + inc1 - cnt[1];
  run[2] = C0 + C1 + wo[wv][2] + inc2 - cnt[2];
  for (int k = 0; k < per; ++k) {
    const int c = lc[k];
    dst[base + k] = (c <= 2) ? run[c]++ : -1;
  }
  const int M = C0 + C1 + C2;
  const int Mpad = (M + 127) & ~127;
  if (t == 0) {
    const int NTv = Mpad >> 7;
    hdr[0] = M;
    hdr[1] = Mpad;
    hdr[2] = NTv;
    hdr[3] = NTv * (NTv + 1) / 2;
    hdr[4] = C0;
    hdr[5] = C1;
    hdr[6] = C2;
    int count = 1;
    if (C0 >= 2 && M > C0) count += C0;
    if (C1 >= 2 && M > C1) count += C1;
    if (C2 >= 2 && M > C2) count += C2;
    hdr[7] = count;
    out[0] = 0.f;
  }
  for (int i = M + t; i < Mpad; i += 1024) gcode[i] = 255;
  const int nv4 = (Mpad - M) * (Dv >> 3);
  float4* fp = (float4*)(fng + (size_t)M * Dv);
  const float4 z = {0.f, 0.f, 0.f, 0.f};
  for (int i = t; i < nv4; i += 1024) fp[i] = z;
}

__global__ __launch_bounds__(128) void k_norm(const float* __restrict__ X,
                                              const unsigned char* __restrict__
                                                  code,
                                              const int* __restrict__ dst,
                                              __bf16* __restrict__ fng,
                                              unsigned char* __restrict__ gcode,
                                              int Dv) {
  const int row = blockIdx.x;
  const unsigned char c = code[row];
  if (c > 2) return;
  const int g = dst[row];
  const int t = threadIdx.x;
  const float4* xr = (const float4*)(X + (size_t)row * Dv);
  const int nv4 = Dv >> 2;
  __shared__ float sred[2];
  if (nv4 == 128) {
    const float4 v = xr[t];
    float ss = v.x * v.x + v.y * v.y + v.z * v.z + v.w * v.w;
#pragma unroll
    for (int off = 32; off; off >>= 1) ss += __shfl_down(ss, off);
    if ((t & 63) == 0) sred[t >> 6] = ss;
    __syncthreads();
    const float inv = 1.0f / sqrtf(sred[0] + sred[1]);
    bf16x4 o;
    o[0] = (__bf16)(v.x * inv);
    o[1] = (__bf16)(v.y * inv);
    o[2] = (__bf16)(v.z * inv);
    o[3] = (__bf16)(v.w * inv);
    *(bf16x4*)(fng + (size_t)g * Dv + t * 4) = o;
    if (t == 0) gcode[g] = c;
    return;
  }
  float ss = 0.f;
  for (int idx = t; idx < nv4; idx += 128) {
    float4 v = xr[idx];
    ss += v.x * v.x + v.y * v.y + v.z * v.z + v.w * v.w;
  }
#pragma unroll
  for (int off = 32; off; off >>= 1) ss += __shfl_down(ss, off);
  if ((t & 63) == 0) sred[t >> 6] = ss;
  __syncthreads();
  const float inv = 1.0f / sqrtf(sred[0] + sred[1]);
  const int nv8 = Dv >> 3;
  for (int idx = t; idx < nv8; idx += 128) {
    const float4 v0 = xr[idx * 2];
    const float4 v1 = xr[idx * 2 + 1];
    bf16x8 o;
    o[0] = (__bf16)(v0.x * inv);
    o[1] = (__bf16)(v0.y * inv);
    o[2] = (__bf16)(v0.z * inv);
    o[3] = (__bf16)(v0.w * inv);
    o[4] = (__bf16)(v1.x * inv);
    o[5] = (__bf16)(v1.y * inv);
    o[6] = (__bf16)(v1.z * inv);
    o[7] = (__bf16)(v1.w * inv);
    *(bf16x8*)(fng + (size_t)g * Dv + idx * 8) = o;
  }
  if (t == 0) gcode[g] = c;
}

__global__ __launch_bounds__(512, 6) void k_p1(
    const __bf16* __restrict__ fng, const unsigned char* __restrict__ gcode,
    const int* __restrict__ hdr, float* __restrict__ P,
    _Float16* __restrict__ Sc, int Dv) {
  const int NTv = hdr[2];
  const int ntri = hdr[3];
  int bid = blockIdx.x;
  if (bid >= ntri) return;
  bid = xcd_swz(bid, ntri);
  int bi, bj;
  tri_decode(bid, NTv, bi, bj);
  const size_t sA = (size_t)bi * 128;
  const size_t rowB = (size_t)bj * 128;
  __shared__ __align__(16) __bf16 As[2][128 * 32];
  __shared__ __align__(16) __bf16 Bs[2][128 * 32];

  const int t = threadIdx.x;
  const int lane = t & 63;
  const int wave = t >> 6;
  const int quad = lane >> 4;
  const int l16 = lane & 15;
  const int wr = (wave >> 1) * 32;
  const int wc = (wave & 1) * 64;
  const int r4 = t >> 2, q4 = t & 3;

  f32x4 acc[2][4] = {};
  auto stage = [&](int k0, int b) {
    GLOAD_LDS16(fng + (sA + r4) * Dv + k0 + q4 * 8,
                &As[b][(size_t)wave * 64 * 8]);
    GLOAD_LDS16(fng + (rowB + r4) * Dv + k0 + q4 * 8,
                &Bs[b][(size_t)wave * 64 * 8]);
  };
  stage(0, 0);
  int buf = 0;
  for (int k0 = 0; k0 < Dv; k0 += 32) {
    __syncthreads();
    if (k0 + 32 < Dv) stage(k0 + 32, buf ^ 1);
    bf16x8 af[2], bfv[4];
#pragma unroll
    for (int mi = 0; mi < 2; ++mi)
      af[mi] = *(const bf16x8*)&As[buf][(wr + mi * 16 + l16) * 32 + quad * 8];
#pragma unroll
    for (int ni = 0; ni < 4; ++ni)
      bfv[ni] = *(const bf16x8*)&Bs[buf][(wc + ni * 16 + l16) * 32 + quad * 8];
#pragma unroll
    for (int mi = 0; mi < 2; ++mi)
#pragma unroll
      for (int ni = 0; ni < 4; ++ni)
        acc[mi][ni] = __builtin_amdgcn_mfma_f32_16x16x32_bf16(
            af[mi], bfv[ni], acc[mi][ni], 0, 0, 0);
    buf ^= 1;
  }
  unsigned char ca[8], cb[4];
#pragma unroll
  for (int mi = 0; mi < 2; ++mi)
#pragma unroll
    for (int r = 0; r < 4; ++r)
      ca[mi * 4 + r] = gcode[sA + wr + mi * 16 + quad * 4 + r];
#pragma unroll
  for (int ni = 0; ni < 4; ++ni) cb[ni] = gcode[rowB + wc + ni * 16 + l16];
  const bool ov = tile_overlap(gcode, sA, 127, rowB);
  _Float16* St = Sc + (size_t)bid * 16384;

  float rowsum[8] = {};
  float colsum[4] = {};
#pragma unroll
  for (int mi = 0; mi < 2; ++mi)
#pragma unroll
    for (int ni = 0; ni < 4; ++ni)
#pragma unroll
      for (int r = 0; r < 4; ++r) {
        const float s = acc[mi][ni][r] * 10.0f;
        const float ex = __expf(s);
        const int a = ca[mi * 4 + r], b = cb[ni];
        const bool diff = a != b;
        rowsum[mi * 4 + r] += (b <= 2 && diff) ? ex : 0.f;
        colsum[ni] += (a <= 2 && diff) ? ex : 0.f;
        if (ov)
          St[(wr + mi * 16 + quad * 4 + r) * 128 + wc + ni * 16 + l16] =
              (_Float16)s;
      }
#pragma unroll
  for (int off = 1; off < 16; off <<= 1)
#pragma unroll
    for (int k = 0; k < 8; ++k) rowsum[k] += __shfl_xor(rowsum[k], off);
  if (l16 == 0)
#pragma unroll
    for (int k = 0; k < 8; ++k) {
      const size_t base =
          (sA + wr + (k >> 2) * 16 + quad * 4 + (k & 3)) * SLOTW + bj * 4;
      P[base + (wave & 1)] = rowsum[k];
      P[base + 2 + (wave & 1)] = 0.f;
    }
  if (bi != bj) {
#pragma unroll
    for (int off = 16; off < 64; off <<= 1)
#pragma unroll
      for (int ni = 0; ni < 4; ++ni) colsum[ni] += __shfl_xor(colsum[ni], off);
    if (quad == 0)
#pragma unroll
      for (int ni = 0; ni < 4; ++ni)
        P[(rowB + wc + ni * 16 + l16) * SLOTW + bi * 4 + (wave >> 1)] =
            colsum[ni];
  }
}

__global__ __launch_bounds__(256) void k_red(const float* __restrict__ P,
                                             float* __restrict__ out,
                                             const int* __restrict__ hdr,
                                             int Nv) {
  const int g = blockIdx.x * 256 + threadIdx.x;
  if (g >= Nv || g >= hdr[1]) return;
  const int ns = hdr[2] * 4;
  float s = 0.f;
  const float4* p = (const float4*)(P + (size_t)g * SLOTW);
  for (int k = 0; k < (ns >> 2); ++k) {
    const float4 v = p[k];
    s += v.x + v.y + v.z + v.w;
  }
  out[g] = s;
}

__global__ __launch_bounds__(256) void k_p2(
    const unsigned char* __restrict__ gcode, const int* __restrict__ hdr,
    const float* __restrict__ E, float* __restrict__ P2,
    const _Float16* __restrict__ Sc) {
  const int NTv = hdr[2];
  const int ntri = hdr[3];
  if ((int)blockIdx.x >= ntri) return;
  const int bid = xcd_swz(blockIdx.x, ntri);
  int bi, bj;
  tri_decode(bid, NTv, bi, bj);
  const int h = blockIdx.y;
  const size_t sA = (size_t)bi * 128 + h * 64;
  const size_t rowB = (size_t)bj * 128;
  const int t = threadIdx.x;
  const bool diag = (bi == bj);

  if (!tile_overlap(gcode, sA, 63, rowB)) {
    if (t < 64) {
      const size_t base = (sA + t) * SLOTW + bj * 4;
      P2[base] = 0.f;
      P2[base + 1] = 0.f;
      P2[base + 2] = 0.f;
      P2[base + 3] = 0.f;
    } else if (t < 192 && !diag) {
      const size_t base = (rowB + t - 64) * SLOTW + bi * 4 + h * 2;
      P2[base] = 0.f;
      P2[base + 1] = 0.f;
    }
    return;
  }

  const _Float16* St = Sc + ((size_t)bid * 2 + h) * 8192;
  const int l8 = t & 15;
  unsigned char cb[8];
  float eB[8];
  {
    const uint2 cv = *(const uint2*)(gcode + rowB + l8 * 8);
    const unsigned char* cp = (const unsigned char*)&cv;
#pragma unroll
    for (int e = 0; e < 8; ++e) cb[e] = cp[e];
    const float4 e0 = *(const float4*)(E + rowB + l8 * 8);
    const float4 e1 = *(const float4*)(E + rowB + l8 * 8 + 4);
    eB[0] = e0.x; eB[1] = e0.y; eB[2] = e0.z; eB[3] = e0.w;
    eB[4] = e1.x; eB[5] = e1.y; eB[6] = e1.z; eB[7] = e1.w;
  }
  float colsum[8] = {};
#pragma unroll
  for (int k = 0; k < 4; ++k) {
    const int row = k * 16 + (t >> 4);
    const int a = gcode[sA + row];
    const float eA = E[sA + row];
    const float4 sv = *(const float4*)(St + row * 128 + l8 * 8);
    const _Float16* hp = (const _Float16*)&sv;
    float rsum = 0.f;
#pragma unroll
    for (int e = 0; e < 8; ++e) {
      const int col = l8 * 8 + e;
      const float em = __expf(-(float)hp[e]);
      const bool pos =
          (a == cb[e]) && (cb[e] <= 2) && !(diag && (row + h * 64) == col);
      rsum += pos ? __logf(1.f + eA * em) : 0.f;
      colsum[e] += pos ? __logf(1.f + eB[e] * em) : 0.f;
    }
#pragma unroll
    for (int off = 1; off < 16; off <<= 1) rsum += __shfl_xor(rsum, off);
    if (l8 == 0) {
      const size_t base = (sA + row) * SLOTW + bj * 4;
      P2[base + h * 2] = rsum;
      P2[base + h * 2 + 1] = 0.f;
      P2[base + (1 - h) * 2] = 0.f;
      P2[base + (1 - h) * 2 + 1] = 0.f;
    }
  }
  __shared__ float colpart[128 * 17];
#pragma unroll
  for (int e = 0; e < 8; ++e) colpart[(l8 * 8 + e) * 17 + (t >> 4)] = colsum[e];
  __syncthreads();
  if (t < 128 && !diag) {
    float cs = 0.f;
#pragma unroll
    for (int i = 0; i < 16; ++i) cs += colpart[t * 17 + i];
    const size_t base = (rowB + t) * SLOTW + bi * 4 + h * 2;
    P2[base] = cs;
    P2[base + 1] = 0.f;
  }
}

__global__ __launch_bounds__(256) void k_fin(const float* __restrict__ P2,
                                             const float* __restrict__ E,
                                             const unsigned char* __restrict__
                                                 gcode,
                                             const int* __restrict__ hdr,
                                             float* __restrict__ out) {
  const int g = blockIdx.x * 256 + threadIdx.x;
  const int t = threadIdx.x;
  float contrib = 0.f;
  if (g < hdr[1]) {
    const int l = gcode[g];
    if (l <= 2) {
      const int c0 = hdr[4], c1 = hdr[5], c2 = hdr[6];
      const int vt = c0 + c1 + c2;
      const int cmy = (l == 0) ? c0 : ((l == 1) ? c1 : c2);
      if (vt - cmy > 0) {
        const int pos_cnt = cmy - 1;
        if (pos_cnt > 0) {
          const int ns = hdr[2] * 4;
          float s = 0.f;
          const float4* p = (const float4*)(P2 + (size_t)g * SLOTW);
          for (int k = 0; k < (ns >> 2); ++k) {
            const float4 v = p[k];
            s += v.x + v.y + v.z + v.w;
          }
          contrib = s / (float)pos_cnt;
        } else {
          contrib = __logf(1.f + E[g] * __expf(-10.0f));
        }
      }
    }
  }
#pragma unroll
  for (int off = 32; off; off >>= 1) contrib += __shfl_down(contrib, off);
  __shared__ float sd[4];
  if ((t & 63) == 0) sd[t >> 6] = contrib;
  __syncthreads();
  if (t == 0) {
    const float tot = sd[0] + sd[1] + sd[2] + sd[3];
    atomicAdd(out, tot / (float)hdr[7]);
  }
}

extern "C" void kernel_launch(void* const* d_in, const int* in_sizes, int n_in,
                              void* d_out, int out_size, void* d_ws,
                              size_t ws_size, hipStream_t stream) {
  const float* X = (const float*)d_in[0];
  const int* labels = (const int*)d_in[1];
  const int* bad = (const int*)d_in[2];
  const int Nv = in_sizes[1];
  const int Dv = in_sizes[0] / Nv;

  size_t off = 0;
  auto alloc = [&](size_t bytes) -> void* {
    size_t p = (off + 255) & ~(size_t)255;
    off = p + bytes;
    return (void*)((char*)d_ws + p);
  };
  const int NT = Nv / 128;
  const int ntri_max = NT * (NT + 1) / 2;
  __bf16* fng = (__bf16*)alloc((size_t)Nv * Dv * 2);
  float* P = (float*)alloc((size_t)Nv * SLOTW * 4);
  float* P2 = (float*)alloc((size_t)Nv * SLOTW * 4);
  _Float16* Sc = (_Float16*)alloc((size_t)ntri_max * 2 * 8192 * 2);
  float* E = (float*)alloc((size_t)Nv * 4);
  int* dst = (int*)alloc((size_t)Nv * 4);
  unsigned char* code = (unsigned char*)alloc((size_t)Nv);
  unsigned char* gcode = (unsigned char*)alloc((size_t)Nv);
  int* hdr = (int*)alloc(64);
  if (off > ws_size) return;
  float* outp = (float*)d_out;

  // cooperative grid sizing (cached; occupancy API guarantees co-residency)
  static int occ = -1;
  if (occ < 0) {
    int o = 0;
    if (hipOccupancyMaxActiveBlocksPerMultiprocessor(&o, k_fused, 512, 0) !=
        hipSuccess)
      o = 0;
    occ = o;
  }
  if (occ >= 1) {
    int G = occ * 256;  // MI355X: 256 CUs
    int NvA = Nv, DvA = Dv;
    void* args[] = {(void*)&X,    (void*)&labels, (void*)&bad,  (void*)&code,
                    (void*)&dst,  (void*)&hdr,    (void*)&fng,  (void*)&gcode,
                    (void*)&P,    (void*)&Sc,     (void*)&P2,   (void*)&outp,
                    (void*)&NvA,  (void*)&DvA};
    if (hipLaunchCooperativeKernel(k_fused, dim3(G), dim3(512), args, 0,
                                   stream) == hipSuccess)
      return;
    (void)hipGetLastError();  // clear, fall through to classic pipeline
  }

  // -------- fallback: R1 pipeline --------
  k_scan<<<1, 1024, 0, stream>>>(labels, bad, code, dst, hdr, fng, gcode,
                                 outp, Nv, Dv);
  k_norm<<<Nv, 128, 0, stream>>>(X, code, dst, fng, gcode, Dv);
  k_p1<<<ntri_max, 512, 0, stream>>>(fng, gcode, hdr, P, Sc, Dv);
  k_red<<<(Nv + 255) / 256, 256, 0, stream>>>(P, E, hdr, Nv);
  dim3 gp(ntri_max, 2);
  k_p2<<<gp, 256, 0, stream>>>(gcode, hdr, E, P2, Sc);
  k_fin<<<(Nv + 255) / 256, 256, 0, stream>>>(P2, E, gcode, hdr, outp);
}

// Round 3
// 135.093 us; speedup vs baseline: 2.3097x; 2.3097x over previous
//
#include <hip/hip_runtime.h>

typedef __bf16 bf16x8 __attribute__((ext_vector_type(8)));
typedef __bf16 bf16x4 __attribute__((ext_vector_type(4)));
typedef float f32x4 __attribute__((ext_vector_type(4)));

#define GLOAD_LDS16(g, l)                                                      \
  __builtin_amdgcn_global_load_lds(                                            \
      (const __attribute__((address_space(1))) void*)(g),                      \
      (__attribute__((address_space(3))) void*)(l), 16, 0, 0)

// R12: P/P2 transposed to [slot][row] (stride Nv). All slot-reduce reads
// (k_red, k_fin) and col-sum stores (k_p1, k_p2) are now lane-coalesced.
// Slot ownership identical to R1 (single writer per slot) — layout-only change.

// ---------------- K1: codes + stable label-partition scan (1 block) ---------
__global__ __launch_bounds__(1024) void k_scan(
    const int* __restrict__ labels, const int* __restrict__ bad,
    unsigned char* __restrict__ code, int* __restrict__ dst,
    int* __restrict__ hdr, __bf16* __restrict__ fng,
    unsigned char* __restrict__ gcode, float* __restrict__ out, int Nv,
    int Dv) {
  const int t = threadIdx.x;
  const int lane = t & 63, wv = t >> 6;
  const int per = Nv >> 10;
  const int base = t * per;
  unsigned char lc[8];
  int cnt[3] = {0, 0, 0};
  for (int k = 0; k < per; ++k) {
    const int r = base + k;
    const unsigned char c =
        (bad[r] == 0) ? (unsigned char)labels[r] : (unsigned char)255;
    lc[k] = c;
    code[r] = c;
    if (c <= 2) cnt[c]++;
  }
  int inc0 = cnt[0], inc1 = cnt[1], inc2 = cnt[2];
#pragma unroll
  for (int off = 1; off < 64; off <<= 1) {
    const int a = __shfl_up(inc0, off);
    const int b = __shfl_up(inc1, off);
    const int c = __shfl_up(inc2, off);
    if (lane >= off) {
      inc0 += a;
      inc1 += b;
      inc2 += c;
    }
  }
  __shared__ int wt[16][3], wo[17][3];
  if (lane == 63) {
    wt[wv][0] = inc0;
    wt[wv][1] = inc1;
    wt[wv][2] = inc2;
  }
  __syncthreads();
  if (t == 0) {
    int s0 = 0, s1 = 0, s2 = 0;
    for (int w = 0; w < 16; ++w) {
      wo[w][0] = s0;
      wo[w][1] = s1;
      wo[w][2] = s2;
      s0 += wt[w][0];
      s1 += wt[w][1];
      s2 += wt[w][2];
    }
    wo[16][0] = s0;
    wo[16][1] = s1;
    wo[16][2] = s2;
  }
  __syncthreads();
  const int C0 = wo[16][0], C1 = wo[16][1], C2 = wo[16][2];
  int run[3];
  run[0] = wo[wv][0] + inc0 - cnt[0];
  run[1] = C0 + wo[wv][1] + inc1 - cnt[1];
  run[2] = C0 + C1 + wo[wv][2] + inc2 - cnt[2];
  for (int k = 0; k < per; ++k) {
    const int c = lc[k];
    dst[base + k] = (c <= 2) ? run[c]++ : -1;
  }
  const int M = C0 + C1 + C2;
  const int Mpad = (M + 127) & ~127;
  if (t == 0) {
    const int NTv = Mpad >> 7;
    hdr[0] = M;
    hdr[1] = Mpad;
    hdr[2] = NTv;
    hdr[3] = NTv * (NTv + 1) / 2;
    hdr[4] = C0;
    hdr[5] = C1;
    hdr[6] = C2;
    int count = 1;
    if (C0 >= 2 && M > C0) count += C0;
    if (C1 >= 2 && M > C1) count += C1;
    if (C2 >= 2 && M > C2) count += C2;
    hdr[7] = count;
    out[0] = 0.f;  // k_fin atomicAdds into this
  }
  for (int i = M + t; i < Mpad; i += 1024) gcode[i] = 255;
  const int nv4 = (Mpad - M) * (Dv >> 3);
  float4* fp = (float4*)(fng + (size_t)M * Dv);
  const float4 z = {0.f, 0.f, 0.f, 0.f};
  for (int i = t; i < nv4; i += 1024) fp[i] = z;
}

// ---------------- K2: normalize, one row per wave (1024 x 512) --------------
__global__ __launch_bounds__(512) void k_norm(const float* __restrict__ X,
                                              const unsigned char* __restrict__
                                                  code,
                                              const int* __restrict__ dst,
                                              __bf16* __restrict__ fng,
                                              unsigned char* __restrict__ gcode,
                                              int Nv, int Dv) {
  const int t = threadIdx.x;
  const int tl = t & 63;
  const int row = blockIdx.x * 8 + (t >> 6);
  if (row >= Nv) return;
  const unsigned char c = code[row];
  if (c > 2) return;  // wave-uniform skip
  const float4* xr = (const float4*)(X + (size_t)row * Dv);
  if (Dv == 512) {
    const float4 v0 = xr[tl * 2];
    const float4 v1 = xr[tl * 2 + 1];
    float ss = v0.x * v0.x + v0.y * v0.y + v0.z * v0.z + v0.w * v0.w +
               v1.x * v1.x + v1.y * v1.y + v1.z * v1.z + v1.w * v1.w;
#pragma unroll
    for (int off = 1; off < 64; off <<= 1) ss += __shfl_xor(ss, off);
    const float inv = 1.0f / sqrtf(ss);
    const int g = dst[row];
    bf16x8 o;
    o[0] = (__bf16)(v0.x * inv);
    o[1] = (__bf16)(v0.y * inv);
    o[2] = (__bf16)(v0.z * inv);
    o[3] = (__bf16)(v0.w * inv);
    o[4] = (__bf16)(v1.x * inv);
    o[5] = (__bf16)(v1.y * inv);
    o[6] = (__bf16)(v1.z * inv);
    o[7] = (__bf16)(v1.w * inv);
    *(bf16x8*)(fng + (size_t)g * Dv + tl * 8) = o;
    if (tl == 0) gcode[g] = c;
    return;
  }
  // generic path
  float ss = 0.f;
  for (int idx = tl; idx < (Dv >> 2); idx += 64) {
    const float4 v = xr[idx];
    ss += v.x * v.x + v.y * v.y + v.z * v.z + v.w * v.w;
  }
#pragma unroll
  for (int off = 1; off < 64; off <<= 1) ss += __shfl_xor(ss, off);
  const float inv = 1.0f / sqrtf(ss);
  const int g = dst[row];
  for (int idx = tl; idx < (Dv >> 3); idx += 64) {
    const float4 u0 = xr[idx * 2];
    const float4 u1 = xr[idx * 2 + 1];
    bf16x8 o;
    o[0] = (__bf16)(u0.x * inv);
    o[1] = (__bf16)(u0.y * inv);
    o[2] = (__bf16)(u0.z * inv);
    o[3] = (__bf16)(u0.w * inv);
    o[4] = (__bf16)(u1.x * inv);
    o[5] = (__bf16)(u1.y * inv);
    o[6] = (__bf16)(u1.z * inv);
    o[7] = (__bf16)(u1.w * inv);
    *(bf16x8*)(fng + (size_t)g * Dv + idx * 8) = o;
  }
  if (tl == 0) gcode[g] = c;
}

__device__ __forceinline__ void tri_decode(int blk, int NT, int& bi, int& bj) {
  int b = 0, rem = blk, span = NT;
  while (rem >= span) {
    rem -= span;
    b++;
    span--;
  }
  bi = b;
  bj = b + rem;
}

// bijective XCD swizzle over [0,n) (m204 formula)
__device__ __forceinline__ int xcd_swz(int w, int n) {
  const int q = n >> 3, r = n & 7, x = w & 7, o = w >> 3;
  return (x < r ? x * (q + 1) : r * (q + 1) + (x - r) * q) + o;
}

__device__ __forceinline__ bool tile_overlap(const unsigned char* gcode,
                                             size_t sA, int lastA,
                                             size_t rowB) {
  const int la0 = gcode[sA], la1 = gcode[sA + lastA];
  const int lb0 = gcode[rowB], lb1 = gcode[rowB + 127];
  const int hiA = la1 > 2 ? 2 : la1;
  const int hiB = lb1 > 2 ? 2 : lb1;
  const int lo = la0 > lb0 ? la0 : lb0;
  const int hi = hiA < hiB ? hiA : hiB;
  return (la0 <= 2) && (lb0 <= 2) && (lo <= hi);
}

// ---------------- K3: pass 1 — exp-sums, 128x128 tiles ----------------------
// 8 waves (4 row x 2 col), 32x64 per wave. P transposed: P[slot*Nv + row].
// Slot ownership per row-tile tg, slot block k*4..k*4+3:
//   k>tg: tile(tg,k) A-path writes all 4 (2 real float4-rows, 2 zero)
//   k<tg: tile(k,tg) B-path (colsum) writes all 4 real (coalesced)
//   k==tg: diag A-path writes all 4
__global__ __launch_bounds__(512, 6) void k_p1(
    const __bf16* __restrict__ fng, const unsigned char* __restrict__ gcode,
    const int* __restrict__ hdr, float* __restrict__ P,
    _Float16* __restrict__ Sc, int Nv, int Dv) {
  const int NTv = hdr[2];
  const int ntri = hdr[3];
  int bid = blockIdx.x;
  if (bid >= ntri) return;
  bid = xcd_swz(bid, ntri);
  int bi, bj;
  tri_decode(bid, NTv, bi, bj);
  const size_t sA = (size_t)bi * 128;
  const size_t rowB = (size_t)bj * 128;
  __shared__ __align__(16) __bf16 As[2][128 * 32];
  __shared__ __align__(16) __bf16 Bs[2][128 * 32];

  const int t = threadIdx.x;
  const int lane = t & 63;
  const int wave = t >> 6;
  const int quad = lane >> 4;
  const int l16 = lane & 15;
  const int wr = (wave >> 1) * 32;
  const int wc = (wave & 1) * 64;
  const int r4 = t >> 2, q4 = t & 3;

  f32x4 acc[2][4] = {};
  auto stage = [&](int k0, int b) {
    GLOAD_LDS16(fng + (sA + r4) * Dv + k0 + q4 * 8,
                &As[b][(size_t)wave * 64 * 8]);
    GLOAD_LDS16(fng + (rowB + r4) * Dv + k0 + q4 * 8,
                &Bs[b][(size_t)wave * 64 * 8]);
  };
  stage(0, 0);
  int buf = 0;
  for (int k0 = 0; k0 < Dv; k0 += 32) {
    __syncthreads();  // drains vmcnt: buf loads done; prev reads done
    if (k0 + 32 < Dv) stage(k0 + 32, buf ^ 1);
    bf16x8 af[2], bfv[4];
#pragma unroll
    for (int mi = 0; mi < 2; ++mi)
      af[mi] = *(const bf16x8*)&As[buf][(wr + mi * 16 + l16) * 32 + quad * 8];
#pragma unroll
    for (int ni = 0; ni < 4; ++ni)
      bfv[ni] = *(const bf16x8*)&Bs[buf][(wc + ni * 16 + l16) * 32 + quad * 8];
#pragma unroll
    for (int mi = 0; mi < 2; ++mi)
#pragma unroll
      for (int ni = 0; ni < 4; ++ni)
        acc[mi][ni] = __builtin_amdgcn_mfma_f32_16x16x32_bf16(
            af[mi], bfv[ni], acc[mi][ni], 0, 0, 0);
    buf ^= 1;
  }
  // C/D layout (verified m89/m91): col = lane&15, row = quad*4 + reg
  unsigned char ca[8], cb[4];
#pragma unroll
  for (int mi = 0; mi < 2; ++mi)
#pragma unroll
    for (int r = 0; r < 4; ++r)
      ca[mi * 4 + r] = gcode[sA + wr + mi * 16 + quad * 4 + r];
#pragma unroll
  for (int ni = 0; ni < 4; ++ni) cb[ni] = gcode[rowB + wc + ni * 16 + l16];
  const bool ov = tile_overlap(gcode, sA, 127, rowB);
  _Float16* St = Sc + (size_t)bid * 16384;

  float rowsum[8] = {};
  float colsum[4] = {};
#pragma unroll
  for (int mi = 0; mi < 2; ++mi)
#pragma unroll
    for (int ni = 0; ni < 4; ++ni)
#pragma unroll
      for (int r = 0; r < 4; ++r) {
        const float s = acc[mi][ni][r] * 10.0f;
        const float ex = __expf(s);
        const int a = ca[mi * 4 + r], b = cb[ni];
        const bool diff = a != b;
        rowsum[mi * 4 + r] += (b <= 2 && diff) ? ex : 0.f;
        colsum[ni] += (a <= 2 && diff) ? ex : 0.f;
        if (ov)
          St[(wr + mi * 16 + quad * 4 + r) * 128 + wc + ni * 16 + l16] =
              (_Float16)s;
      }
#pragma unroll
  for (int off = 1; off < 16; off <<= 1)
#pragma unroll
    for (int k = 0; k < 8; ++k) rowsum[k] += __shfl_xor(rowsum[k], off);
  if (l16 == 0) {
    // transposed float4 stores: rows sA+wr+{0,16}+quad*4 .. +3
    const int sreal = bj * 4 + (wave & 1);
    const int szero = bj * 4 + 2 + (wave & 1);
    const size_t r0 = sA + wr + quad * 4;
    float4 v0 = {rowsum[0], rowsum[1], rowsum[2], rowsum[3]};
    float4 v1 = {rowsum[4], rowsum[5], rowsum[6], rowsum[7]};
    const float4 z = {0.f, 0.f, 0.f, 0.f};
    *(float4*)(P + (size_t)sreal * Nv + r0) = v0;
    *(float4*)(P + (size_t)sreal * Nv + r0 + 16) = v1;
    *(float4*)(P + (size_t)szero * Nv + r0) = z;
    *(float4*)(P + (size_t)szero * Nv + r0 + 16) = z;
  }
  if (bi != bj) {
#pragma unroll
    for (int off = 16; off < 64; off <<= 1)
#pragma unroll
      for (int ni = 0; ni < 4; ++ni) colsum[ni] += __shfl_xor(colsum[ni], off);
    if (quad == 0) {
      const int s = bi * 4 + (wave >> 1);
#pragma unroll
      for (int ni = 0; ni < 4; ++ni)
        P[(size_t)s * Nv + rowB + wc + ni * 16 + l16] = colsum[ni];
    }
  }
}

// ---------------- K4: slot reduce: E[g] = sum_k P[k*Nv+g] (coalesced) -------
__global__ __launch_bounds__(256) void k_red(const float* __restrict__ P,
                                             float* __restrict__ out,
                                             const int* __restrict__ hdr,
                                             int Nv) {
  const int g = blockIdx.x * 256 + threadIdx.x;
  if (g >= Nv || g >= hdr[1]) return;
  const int ns = hdr[2] * 4;
  float s0 = 0.f, s1 = 0.f, s2 = 0.f, s3 = 0.f;
  int k = 0;
  for (; k + 4 <= ns; k += 4) {
    s0 += P[(size_t)k * Nv + g];
    s1 += P[(size_t)(k + 1) * Nv + g];
    s2 += P[(size_t)(k + 2) * Nv + g];
    s3 += P[(size_t)(k + 3) * Nv + g];
  }
  for (; k < ns; ++k) s0 += P[(size_t)k * Nv + g];
  out[g] = (s0 + s1) + (s2 + s3);
}

// ---------------- K5: pass 2 — positive log-terms from stored Sc ------------
// P2 transposed [slot][row]. Ownership (as R1, layout changed only):
//   row g (A-side, half h): slots bj*4+{0..3} (real at h*2, zeros elsewhere)
//   col j (B-side): slots bi*4+h*2 (real), +1 (zero)
__global__ __launch_bounds__(256) void k_p2(
    const unsigned char* __restrict__ gcode, const int* __restrict__ hdr,
    const float* __restrict__ E, float* __restrict__ P2,
    const _Float16* __restrict__ Sc, int Nv) {
  const int NTv = hdr[2];
  if ((int)blockIdx.x >= hdr[3]) return;
  int bi, bj;
  tri_decode(blockIdx.x, NTv, bi, bj);
  const int h = blockIdx.y;
  const size_t sA = (size_t)bi * 128 + h * 64;
  const size_t rowB = (size_t)bj * 128;
  const int t = threadIdx.x;
  const bool diag = (bi == bj);

  if (!tile_overlap(gcode, sA, 63, rowB)) {
    if (t < 64) {
      const size_t r = sA + t;
      P2[(size_t)(bj * 4 + 0) * Nv + r] = 0.f;
      P2[(size_t)(bj * 4 + 1) * Nv + r] = 0.f;
      P2[(size_t)(bj * 4 + 2) * Nv + r] = 0.f;
      P2[(size_t)(bj * 4 + 3) * Nv + r] = 0.f;
    } else if (t < 192 && !diag) {
      const size_t r = rowB + t - 64;
      P2[(size_t)(bi * 4 + h * 2) * Nv + r] = 0.f;
      P2[(size_t)(bi * 4 + h * 2 + 1) * Nv + r] = 0.f;
    }
    return;
  }

  const _Float16* St = Sc + ((size_t)blockIdx.x * 2 + h) * 8192;
  const int l8 = t & 15;
  unsigned char cb[8];
  float eB[8];
  {
    const uint2 cv = *(const uint2*)(gcode + rowB + l8 * 8);
    const unsigned char* cp = (const unsigned char*)&cv;
#pragma unroll
    for (int e = 0; e < 8; ++e) cb[e] = cp[e];
    const float4 e0 = *(const float4*)(E + rowB + l8 * 8);
    const float4 e1 = *(const float4*)(E + rowB + l8 * 8 + 4);
    eB[0] = e0.x; eB[1] = e0.y; eB[2] = e0.z; eB[3] = e0.w;
    eB[4] = e1.x; eB[5] = e1.y; eB[6] = e1.z; eB[7] = e1.w;
  }
  float colsum[8] = {};
#pragma unroll
  for (int k = 0; k < 4; ++k) {
    const int row = k * 16 + (t >> 4);
    const int a = gcode[sA + row];
    const float eA = E[sA + row];
    const float4 sv = *(const float4*)(St + row * 128 + l8 * 8);
    const _Float16* hp = (const _Float16*)&sv;
    float rsum = 0.f;
#pragma unroll
    for (int e = 0; e < 8; ++e) {
      const int col = l8 * 8 + e;
      const float em = __expf(-(float)hp[e]);
      const bool pos =
          (a == cb[e]) && (cb[e] <= 2) && !(diag && (row + h * 64) == col);
      rsum += pos ? __logf(1.f + eA * em) : 0.f;
      colsum[e] += pos ? __logf(1.f + eB[e] * em) : 0.f;
    }
#pragma unroll
    for (int off = 1; off < 16; off <<= 1) rsum += __shfl_xor(rsum, off);
    if (l8 == 0) {
      const size_t r = sA + row;
      P2[(size_t)(bj * 4 + h * 2) * Nv + r] = rsum;
      P2[(size_t)(bj * 4 + h * 2 + 1) * Nv + r] = 0.f;
      P2[(size_t)(bj * 4 + (1 - h) * 2) * Nv + r] = 0.f;
      P2[(size_t)(bj * 4 + (1 - h) * 2 + 1) * Nv + r] = 0.f;
    }
  }
  __shared__ float colpart[128 * 17];
#pragma unroll
  for (int e = 0; e < 8; ++e) colpart[(l8 * 8 + e) * 17 + (t >> 4)] = colsum[e];
  __syncthreads();
  if (t < 128 && !diag) {
    float cs = 0.f;
#pragma unroll
    for (int i = 0; i < 16; ++i) cs += colpart[t * 17 + i];
    const size_t r = rowB + t;
    P2[(size_t)(bi * 4 + h * 2) * Nv + r] = cs;
    P2[(size_t)(bi * 4 + h * 2 + 1) * Nv + r] = 0.f;
  }
}

// ---------------- K6: fused slot-reduce + final loss ------------------------
__global__ __launch_bounds__(256) void k_fin(const float* __restrict__ P2,
                                             const float* __restrict__ E,
                                             const unsigned char* __restrict__
                                                 gcode,
                                             const int* __restrict__ hdr,
                                             float* __restrict__ out, int Nv) {
  const int g = blockIdx.x * 256 + threadIdx.x;
  const int t = threadIdx.x;
  float contrib = 0.f;
  if (g < hdr[1]) {
    const int l = gcode[g];
    if (l <= 2) {
      const int c0 = hdr[4], c1 = hdr[5], c2 = hdr[6];
      const int vt = c0 + c1 + c2;
      const int cmy = (l == 0) ? c0 : ((l == 1) ? c1 : c2);
      if (vt - cmy > 0) {  // has negatives -> processed
        const int pos_cnt = cmy - 1;
        if (pos_cnt > 0) {
          const int ns = hdr[2] * 4;
          float s0 = 0.f, s1 = 0.f, s2 = 0.f, s3 = 0.f;
          int k = 0;
          for (; k + 4 <= ns; k += 4) {
            s0 += P2[(size_t)k * Nv + g];
            s1 += P2[(size_t)(k + 1) * Nv + g];
            s2 += P2[(size_t)(k + 2) * Nv + g];
            s3 += P2[(size_t)(k + 3) * Nv + g];
          }
          for (; k < ns; ++k) s0 += P2[(size_t)k * Nv + g];
          contrib = ((s0 + s1) + (s2 + s3)) / (float)pos_cnt;
        } else {
          contrib = __logf(1.f + E[g] * __expf(-10.0f));
        }
      }
    }
  }
#pragma unroll
  for (int off = 32; off; off >>= 1) contrib += __shfl_down(contrib, off);
  __shared__ float sd[4];
  if ((t & 63) == 0) sd[t >> 6] = contrib;
  __syncthreads();
  if (t == 0) {
    const float tot = sd[0] + sd[1] + sd[2] + sd[3];
    atomicAdd(out, tot / (float)hdr[7]);
  }
}

extern "C" void kernel_launch(void* const* d_in, const int* in_sizes, int n_in,
                              void* d_out, int out_size, void* d_ws,
                              size_t ws_size, hipStream_t stream) {
  const float* X = (const float*)d_in[0];
  const int* labels = (const int*)d_in[1];
  const int* bad = (const int*)d_in[2];
  const int Nv = in_sizes[1];
  const int Dv = in_sizes[0] / Nv;

  size_t off = 0;
  auto alloc = [&](size_t bytes) -> void* {
    size_t p = (off + 255) & ~(size_t)255;
    off = p + bytes;
    return (void*)((char*)d_ws + p);
  };
  const int NT = Nv / 128;
  const int ntri_max = NT * (NT + 1) / 2;
  __bf16* fng = (__bf16*)alloc((size_t)Nv * Dv * 2);
  float* P = (float*)alloc((size_t)Nv * 256 * 4);   // [slot][row]
  float* P2 = (float*)alloc((size_t)Nv * 256 * 4);  // [slot][row]
  _Float16* Sc = (_Float16*)alloc((size_t)ntri_max * 2 * 8192 * 2);
  float* E = (float*)alloc((size_t)Nv * 4);
  int* dst = (int*)alloc((size_t)Nv * 4);
  unsigned char* code = (unsigned char*)alloc((size_t)Nv);
  unsigned char* gcode = (unsigned char*)alloc((size_t)Nv);
  int* hdr = (int*)alloc(64);
  if (off > ws_size) return;
  float* outp = (float*)d_out;

  k_scan<<<1, 1024, 0, stream>>>(labels, bad, code, dst, hdr, fng, gcode,
                                 outp, Nv, Dv);
  k_norm<<<(Nv + 7) / 8, 512, 0, stream>>>(X, code, dst, fng, gcode, Nv, Dv);
  k_p1<<<ntri_max, 512, 0, stream>>>(fng, gcode, hdr, P, Sc, Nv, Dv);
  k_red<<<(Nv + 255) / 256, 256, 0, stream>>>(P, E, hdr, Nv);
  dim3 gp(ntri_max, 2);
  k_p2<<<gp, 256, 0, stream>>>(gcode, hdr, E, P2, Sc, Nv);
  k_fin<<<(Nv + 255) / 256, 256, 0, stream>>>(P2, E, gcode, hdr, outp, Nv);
}

// Round 4
// 125.635 us; speedup vs baseline: 2.4836x; 1.0753x over previous
//
#include <hip/hip_runtime.h>

typedef __bf16 bf16x8 __attribute__((ext_vector_type(8)));
typedef __bf16 bf16x4 __attribute__((ext_vector_type(4)));
typedef float f32x4 __attribute__((ext_vector_type(4)));

#define GLOAD_LDS16(g, l)                                                      \
  __builtin_amdgcn_global_load_lds(                                            \
      (const __attribute__((address_space(1))) void*)(g),                      \
      (__attribute__((address_space(3))) void*)(l), 16, 0, 0)

// R13: 4-launch pipeline. P stays [slot][row] transposed (R12). k_red folded
// into k_p2 (per-tile E recompute from P, coalesced). k_fin + P2 eliminated:
// each p2 block atomicAdds its loss partial (division by pos_cnt distributes
// over the tile sum; count is in hdr). Diag tiles handle no-pos rows.

// ---------------- K1: codes + stable label-partition scan (1 block) ---------
__global__ __launch_bounds__(1024) void k_scan(
    const int* __restrict__ labels, const int* __restrict__ bad,
    unsigned char* __restrict__ code, int* __restrict__ dst,
    int* __restrict__ hdr, __bf16* __restrict__ fng,
    unsigned char* __restrict__ gcode, float* __restrict__ out, int Nv,
    int Dv) {
  const int t = threadIdx.x;
  const int lane = t & 63, wv = t >> 6;
  const int per = Nv >> 10;
  const int base = t * per;
  unsigned char lc[8];
  int cnt[3] = {0, 0, 0};
  for (int k = 0; k < per; ++k) {
    const int r = base + k;
    const unsigned char c =
        (bad[r] == 0) ? (unsigned char)labels[r] : (unsigned char)255;
    lc[k] = c;
    code[r] = c;
    if (c <= 2) cnt[c]++;
  }
  int inc0 = cnt[0], inc1 = cnt[1], inc2 = cnt[2];
#pragma unroll
  for (int off = 1; off < 64; off <<= 1) {
    const int a = __shfl_up(inc0, off);
    const int b = __shfl_up(inc1, off);
    const int c = __shfl_up(inc2, off);
    if (lane >= off) {
      inc0 += a;
      inc1 += b;
      inc2 += c;
    }
  }
  __shared__ int wt[16][3], wo[17][3];
  if (lane == 63) {
    wt[wv][0] = inc0;
    wt[wv][1] = inc1;
    wt[wv][2] = inc2;
  }
  __syncthreads();
  if (t == 0) {
    int s0 = 0, s1 = 0, s2 = 0;
    for (int w = 0; w < 16; ++w) {
      wo[w][0] = s0;
      wo[w][1] = s1;
      wo[w][2] = s2;
      s0 += wt[w][0];
      s1 += wt[w][1];
      s2 += wt[w][2];
    }
    wo[16][0] = s0;
    wo[16][1] = s1;
    wo[16][2] = s2;
  }
  __syncthreads();
  const int C0 = wo[16][0], C1 = wo[16][1], C2 = wo[16][2];
  int run[3];
  run[0] = wo[wv][0] + inc0 - cnt[0];
  run[1] = C0 + wo[wv][1] + inc1 - cnt[1];
  run[2] = C0 + C1 + wo[wv][2] + inc2 - cnt[2];
  for (int k = 0; k < per; ++k) {
    const int c = lc[k];
    dst[base + k] = (c <= 2) ? run[c]++ : -1;
  }
  const int M = C0 + C1 + C2;
  const int Mpad = (M + 127) & ~127;
  if (t == 0) {
    const int NTv = Mpad >> 7;
    hdr[0] = M;
    hdr[1] = Mpad;
    hdr[2] = NTv;
    hdr[3] = NTv * (NTv + 1) / 2;
    hdr[4] = C0;
    hdr[5] = C1;
    hdr[6] = C2;
    int count = 1;
    if (C0 >= 2 && M > C0) count += C0;
    if (C1 >= 2 && M > C1) count += C1;
    if (C2 >= 2 && M > C2) count += C2;
    hdr[7] = count;
    out[0] = 0.f;  // k_p2 atomicAdds into this
  }
  for (int i = M + t; i < Mpad; i += 1024) gcode[i] = 255;
  const int nv4 = (Mpad - M) * (Dv >> 3);
  float4* fp = (float4*)(fng + (size_t)M * Dv);
  const float4 z = {0.f, 0.f, 0.f, 0.f};
  for (int i = t; i < nv4; i += 1024) fp[i] = z;
}

// ---------------- K2: normalize, one row per wave ---------------------------
__global__ __launch_bounds__(512) void k_norm(const float* __restrict__ X,
                                              const unsigned char* __restrict__
                                                  code,
                                              const int* __restrict__ dst,
                                              __bf16* __restrict__ fng,
                                              unsigned char* __restrict__ gcode,
                                              int Nv, int Dv) {
  const int t = threadIdx.x;
  const int tl = t & 63;
  const int row = blockIdx.x * 8 + (t >> 6);
  if (row >= Nv) return;
  const unsigned char c = code[row];
  if (c > 2) return;  // wave-uniform skip
  const float4* xr = (const float4*)(X + (size_t)row * Dv);
  if (Dv == 512) {
    const float4 v0 = xr[tl * 2];
    const float4 v1 = xr[tl * 2 + 1];
    float ss = v0.x * v0.x + v0.y * v0.y + v0.z * v0.z + v0.w * v0.w +
               v1.x * v1.x + v1.y * v1.y + v1.z * v1.z + v1.w * v1.w;
#pragma unroll
    for (int off = 1; off < 64; off <<= 1) ss += __shfl_xor(ss, off);
    const float inv = 1.0f / sqrtf(ss);
    const int g = dst[row];
    bf16x8 o;
    o[0] = (__bf16)(v0.x * inv);
    o[1] = (__bf16)(v0.y * inv);
    o[2] = (__bf16)(v0.z * inv);
    o[3] = (__bf16)(v0.w * inv);
    o[4] = (__bf16)(v1.x * inv);
    o[5] = (__bf16)(v1.y * inv);
    o[6] = (__bf16)(v1.z * inv);
    o[7] = (__bf16)(v1.w * inv);
    *(bf16x8*)(fng + (size_t)g * Dv + tl * 8) = o;
    if (tl == 0) gcode[g] = c;
    return;
  }
  // generic path
  float ss = 0.f;
  for (int idx = tl; idx < (Dv >> 2); idx += 64) {
    const float4 v = xr[idx];
    ss += v.x * v.x + v.y * v.y + v.z * v.z + v.w * v.w;
  }
#pragma unroll
  for (int off = 1; off < 64; off <<= 1) ss += __shfl_xor(ss, off);
  const float inv = 1.0f / sqrtf(ss);
  const int g = dst[row];
  for (int idx = tl; idx < (Dv >> 3); idx += 64) {
    const float4 u0 = xr[idx * 2];
    const float4 u1 = xr[idx * 2 + 1];
    bf16x8 o;
    o[0] = (__bf16)(u0.x * inv);
    o[1] = (__bf16)(u0.y * inv);
    o[2] = (__bf16)(u0.z * inv);
    o[3] = (__bf16)(u0.w * inv);
    o[4] = (__bf16)(u1.x * inv);
    o[5] = (__bf16)(u1.y * inv);
    o[6] = (__bf16)(u1.z * inv);
    o[7] = (__bf16)(u1.w * inv);
    *(bf16x8*)(fng + (size_t)g * Dv + idx * 8) = o;
  }
  if (tl == 0) gcode[g] = c;
}

__device__ __forceinline__ void tri_decode(int blk, int NT, int& bi, int& bj) {
  int b = 0, rem = blk, span = NT;
  while (rem >= span) {
    rem -= span;
    b++;
    span--;
  }
  bi = b;
  bj = b + rem;
}

// bijective XCD swizzle over [0,n) (m204 formula)
__device__ __forceinline__ int xcd_swz(int w, int n) {
  const int q = n >> 3, r = n & 7, x = w & 7, o = w >> 3;
  return (x < r ? x * (q + 1) : r * (q + 1) + (x - r) * q) + o;
}

__device__ __forceinline__ bool tile_overlap(const unsigned char* gcode,
                                             size_t sA, int lastA,
                                             size_t rowB) {
  const int la0 = gcode[sA], la1 = gcode[sA + lastA];
  const int lb0 = gcode[rowB], lb1 = gcode[rowB + 127];
  const int hiA = la1 > 2 ? 2 : la1;
  const int hiB = lb1 > 2 ? 2 : lb1;
  const int lo = la0 > lb0 ? la0 : lb0;
  const int hi = hiA < hiB ? hiA : hiB;
  return (la0 <= 2) && (lb0 <= 2) && (lo <= hi);
}

// ---------------- K3: pass 1 — exp-sums, 128x128 tiles (unchanged R12) ------
__global__ __launch_bounds__(512, 6) void k_p1(
    const __bf16* __restrict__ fng, const unsigned char* __restrict__ gcode,
    const int* __restrict__ hdr, float* __restrict__ P,
    _Float16* __restrict__ Sc, int Nv, int Dv) {
  const int NTv = hdr[2];
  const int ntri = hdr[3];
  int bid = blockIdx.x;
  if (bid >= ntri) return;
  bid = xcd_swz(bid, ntri);
  int bi, bj;
  tri_decode(bid, NTv, bi, bj);
  const size_t sA = (size_t)bi * 128;
  const size_t rowB = (size_t)bj * 128;
  __shared__ __align__(16) __bf16 As[2][128 * 32];
  __shared__ __align__(16) __bf16 Bs[2][128 * 32];

  const int t = threadIdx.x;
  const int lane = t & 63;
  const int wave = t >> 6;
  const int quad = lane >> 4;
  const int l16 = lane & 15;
  const int wr = (wave >> 1) * 32;
  const int wc = (wave & 1) * 64;
  const int r4 = t >> 2, q4 = t & 3;

  f32x4 acc[2][4] = {};
  auto stage = [&](int k0, int b) {
    GLOAD_LDS16(fng + (sA + r4) * Dv + k0 + q4 * 8,
                &As[b][(size_t)wave * 64 * 8]);
    GLOAD_LDS16(fng + (rowB + r4) * Dv + k0 + q4 * 8,
                &Bs[b][(size_t)wave * 64 * 8]);
  };
  stage(0, 0);
  int buf = 0;
  for (int k0 = 0; k0 < Dv; k0 += 32) {
    __syncthreads();  // drains vmcnt: buf loads done; prev reads done
    if (k0 + 32 < Dv) stage(k0 + 32, buf ^ 1);
    bf16x8 af[2], bfv[4];
#pragma unroll
    for (int mi = 0; mi < 2; ++mi)
      af[mi] = *(const bf16x8*)&As[buf][(wr + mi * 16 + l16) * 32 + quad * 8];
#pragma unroll
    for (int ni = 0; ni < 4; ++ni)
      bfv[ni] = *(const bf16x8*)&Bs[buf][(wc + ni * 16 + l16) * 32 + quad * 8];
#pragma unroll
    for (int mi = 0; mi < 2; ++mi)
#pragma unroll
      for (int ni = 0; ni < 4; ++ni)
        acc[mi][ni] = __builtin_amdgcn_mfma_f32_16x16x32_bf16(
            af[mi], bfv[ni], acc[mi][ni], 0, 0, 0);
    buf ^= 1;
  }
  // C/D layout (verified m89/m91): col = lane&15, row = quad*4 + reg
  unsigned char ca[8], cb[4];
#pragma unroll
  for (int mi = 0; mi < 2; ++mi)
#pragma unroll
    for (int r = 0; r < 4; ++r)
      ca[mi * 4 + r] = gcode[sA + wr + mi * 16 + quad * 4 + r];
#pragma unroll
  for (int ni = 0; ni < 4; ++ni) cb[ni] = gcode[rowB + wc + ni * 16 + l16];
  const bool ov = tile_overlap(gcode, sA, 127, rowB);
  _Float16* St = Sc + (size_t)bid * 16384;

  float rowsum[8] = {};
  float colsum[4] = {};
#pragma unroll
  for (int mi = 0; mi < 2; ++mi)
#pragma unroll
    for (int ni = 0; ni < 4; ++ni)
#pragma unroll
      for (int r = 0; r < 4; ++r) {
        const float s = acc[mi][ni][r] * 10.0f;
        const float ex = __expf(s);
        const int a = ca[mi * 4 + r], b = cb[ni];
        const bool diff = a != b;
        rowsum[mi * 4 + r] += (b <= 2 && diff) ? ex : 0.f;
        colsum[ni] += (a <= 2 && diff) ? ex : 0.f;
        if (ov)
          St[(wr + mi * 16 + quad * 4 + r) * 128 + wc + ni * 16 + l16] =
              (_Float16)s;
      }
#pragma unroll
  for (int off = 1; off < 16; off <<= 1)
#pragma unroll
    for (int k = 0; k < 8; ++k) rowsum[k] += __shfl_xor(rowsum[k], off);
  if (l16 == 0) {
    const int sreal = bj * 4 + (wave & 1);
    const int szero = bj * 4 + 2 + (wave & 1);
    const size_t r0 = sA + wr + quad * 4;
    float4 v0 = {rowsum[0], rowsum[1], rowsum[2], rowsum[3]};
    float4 v1 = {rowsum[4], rowsum[5], rowsum[6], rowsum[7]};
    const float4 z = {0.f, 0.f, 0.f, 0.f};
    *(float4*)(P + (size_t)sreal * Nv + r0) = v0;
    *(float4*)(P + (size_t)sreal * Nv + r0 + 16) = v1;
    *(float4*)(P + (size_t)szero * Nv + r0) = z;
    *(float4*)(P + (size_t)szero * Nv + r0 + 16) = z;
  }
  if (bi != bj) {
#pragma unroll
    for (int off = 16; off < 64; off <<= 1)
#pragma unroll
      for (int ni = 0; ni < 4; ++ni) colsum[ni] += __shfl_xor(colsum[ni], off);
    if (quad == 0) {
      const int s = bi * 4 + (wave >> 1);
#pragma unroll
      for (int ni = 0; ni < 4; ++ni)
        P[(size_t)s * Nv + rowB + wc + ni * 16 + l16] = colsum[ni];
    }
  }
}

// ---------------- K4: pass 2 + final loss (fused, atomic) -------------------
// Full 128x128 tile per block (256 thr). E recomputed from P (coalesced:
// threads 0..127 cover A rows, 128..255 B rows). Each block atomicAdds
// (tile loss partial)/count. Diag tiles also add no-pos terms for their rows.
// Non-overlap tiles contribute nothing (no P2 buffer at all).
__global__ __launch_bounds__(256) void k_p2(
    const unsigned char* __restrict__ gcode, const int* __restrict__ hdr,
    const float* __restrict__ P, const _Float16* __restrict__ Sc,
    float* __restrict__ out, int Nv) {
  const int NTv = hdr[2];
  const int ntri = hdr[3];
  if ((int)blockIdx.x >= ntri) return;
  const int bid = xcd_swz(blockIdx.x, ntri);
  int bi, bj;
  tri_decode(bid, NTv, bi, bj);
  const size_t sA = (size_t)bi * 128;
  const size_t rowB = (size_t)bj * 128;
  const int t = threadIdx.x;
  const bool diag = (bi == bj);
  if (!tile_overlap(gcode, sA, 127, rowB)) return;

  const int c0 = hdr[4], c1 = hdr[5], c2 = hdr[6];
  const int vt = c0 + c1 + c2;
  __shared__ float E_s[256];
  __shared__ float colpart[128 * 17];
  __shared__ float sd[4];

  {  // E recompute from P, coalesced (consecutive t -> consecutive rows)
    const int ns = NTv * 4;
    const size_t g = (t < 128) ? (sA + t) : (rowB + (t - 128));
    float s0 = 0.f, s1 = 0.f, s2 = 0.f, s3 = 0.f;
    int k = 0;
    for (; k + 4 <= ns; k += 4) {
      s0 += P[(size_t)k * Nv + g];
      s1 += P[(size_t)(k + 1) * Nv + g];
      s2 += P[(size_t)(k + 2) * Nv + g];
      s3 += P[(size_t)(k + 3) * Nv + g];
    }
    for (; k < ns; ++k) s0 += P[(size_t)k * Nv + g];
    E_s[t] = (s0 + s1) + (s2 + s3);
  }
  __syncthreads();

  const _Float16* St = Sc + (size_t)bid * 16384;
  const int l8 = t & 15;  // col chunk: cols l8*8 .. +7
  const int rg = t >> 4;  // row group 0..15
  unsigned char cbv[8];
  float eB[8];
  {
    const uint2 cv = *(const uint2*)(gcode + rowB + l8 * 8);
    const unsigned char* cp = (const unsigned char*)&cv;
#pragma unroll
    for (int e = 0; e < 8; ++e) cbv[e] = cp[e];
#pragma unroll
    for (int e = 0; e < 8; ++e) eB[e] = E_s[128 + l8 * 8 + e];
  }
  float colsum[8] = {};
  float part = 0.f;
#pragma unroll
  for (int k = 0; k < 8; ++k) {
    const int row = k * 16 + rg;
    const int a = gcode[sA + row];
    const float eA = E_s[row];
    const float4 sv = *(const float4*)(St + (size_t)row * 128 + l8 * 8);
    const _Float16* hp = (const _Float16*)&sv;
    float rsum = 0.f;
#pragma unroll
    for (int e = 0; e < 8; ++e) {
      const int col = l8 * 8 + e;
      const float em = __expf(-(float)hp[e]);
      const bool pos =
          (a == cbv[e]) && (cbv[e] <= 2) && !(diag && row == col);
      rsum += pos ? __logf(1.f + eA * em) : 0.f;
      colsum[e] += pos ? __logf(1.f + eB[e] * em) : 0.f;
    }
#pragma unroll
    for (int off = 1; off < 16; off <<= 1) rsum += __shfl_xor(rsum, off);
    if (l8 == 0 && a <= 2) {
      const int cmy = (a == 0) ? c0 : ((a == 1) ? c1 : c2);
      if (vt - cmy > 0 && cmy >= 2) part += rsum / (float)(cmy - 1);
    }
  }
#pragma unroll
  for (int e = 0; e < 8; ++e) colpart[(l8 * 8 + e) * 17 + rg] = colsum[e];
  __syncthreads();
  if (t < 128 && !diag) {
    float cs = 0.f;
#pragma unroll
    for (int i = 0; i < 16; ++i) cs += colpart[t * 17 + i];
    const int b = gcode[rowB + t];
    if (b <= 2) {
      const int cmy = (b == 0) ? c0 : ((b == 1) ? c1 : c2);
      if (vt - cmy > 0 && cmy >= 2) part += cs / (float)(cmy - 1);
    }
  }
  if (diag && t < 128) {  // no-pos anchors (pos_cnt==0, has_neg)
    const int a = gcode[sA + t];
    if (a <= 2) {
      const int cmy = (a == 0) ? c0 : ((a == 1) ? c1 : c2);
      if (vt - cmy > 0 && cmy == 1)
        part += __logf(1.f + E_s[t] * __expf(-10.0f));
    }
  }
  // block reduce + single atomic
#pragma unroll
  for (int off = 32; off; off >>= 1) part += __shfl_down(part, off);
  if ((t & 63) == 0) sd[t >> 6] = part;
  __syncthreads();
  if (t == 0) {
    const float tot = sd[0] + sd[1] + sd[2] + sd[3];
    atomicAdd(out, tot / (float)hdr[7]);
  }
}

extern "C" void kernel_launch(void* const* d_in, const int* in_sizes, int n_in,
                              void* d_out, int out_size, void* d_ws,
                              size_t ws_size, hipStream_t stream) {
  const float* X = (const float*)d_in[0];
  const int* labels = (const int*)d_in[1];
  const int* bad = (const int*)d_in[2];
  const int Nv = in_sizes[1];
  const int Dv = in_sizes[0] / Nv;

  size_t off = 0;
  auto alloc = [&](size_t bytes) -> void* {
    size_t p = (off + 255) & ~(size_t)255;
    off = p + bytes;
    return (void*)((char*)d_ws + p);
  };
  const int NT = Nv / 128;
  const int ntri_max = NT * (NT + 1) / 2;
  __bf16* fng = (__bf16*)alloc((size_t)Nv * Dv * 2);
  float* P = (float*)alloc((size_t)Nv * 256 * 4);  // [slot][row]
  _Float16* Sc = (_Float16*)alloc((size_t)ntri_max * 16384 * 2);
  int* dst = (int*)alloc((size_t)Nv * 4);
  unsigned char* code = (unsigned char*)alloc((size_t)Nv);
  unsigned char* gcode = (unsigned char*)alloc((size_t)Nv);
  int* hdr = (int*)alloc(64);
  if (off > ws_size) return;  // scratch too small: fail loudly at validation
  float* outp = (float*)d_out;

  k_scan<<<1, 1024, 0, stream>>>(labels, bad, code, dst, hdr, fng, gcode,
                                 outp, Nv, Dv);
  k_norm<<<(Nv + 7) / 8, 512, 0, stream>>>(X, code, dst, fng, gcode, Nv, Dv);
  k_p1<<<ntri_max, 512, 0, stream>>>(fng, gcode, hdr, P, Sc, Nv, Dv);
  k_p2<<<ntri_max, 256, 0, stream>>>(gcode, hdr, P, Sc, outp, Nv);
}